// Round 11
// baseline (188.367 us; speedup 1.0000x reference)
//
#include <hip/hip_runtime.h>
#include <hip/hip_bf16.h>
#include <hip/hip_fp8.h>

// CrossViewContrast: loss = -mean_i( 2*<z1n_i,z2n_i> - log(sum_j exp(2*<z1n_i,z2n_j>) + 1e-8) )
// N=16384, D=128.
// R8:  MX-fp8 K=128 MFMA, 3 kernels, (256,8): sim 47.7us, total 111.5.
// R11: + stride-4 granule placement -> SQ_LDS_BANK_CONFLICT == 0. sim 47.5, total 112.2.
// R12: JCHUNK 64: NULL. R16: 2-deep pacc, clean: NULL (47.0, total 110.7 best).
// R17: counted-vmcnt pipeline, clean: NULL (50.2). R13/R14/R15/R18/R19: VGPR spills.
// R20: oversubscribed grid, clean (VGPR 32): Occupancy 51->63, VALUBusy 53->59,
//   sim UNCHANGED 47. Residency is not the limiter.
// Pipe accounting per CU @47us: DS pipe ~21-24us (1.05M ds_read_b128 x 12cyc + DMA
//   + barriers) is the LARGEST pipe -- bigger than matrix (14.2us, MfmaUtil 30%)
//   and trans (13.6us). z2q is 2MB = fully L2-resident; per-chunk 4KB is
//   L1-resident after one wave touches it. LDS staging of cache-fit data is
//   Common-mistake #7 (m169: dropping staging at L2-fit = +26%).
// R21 (resubmit -- prior round was an infra failure, container died, no data):
//   DELETE the LDS entirely. B-fragments load straight from global (same lane
//   pattern as the afrag prologue): lane(q,l15) reads rows c*32+jj*16+l15, two
//   dwordx4 at q*32. No lds, no STAGE, no barriers, no granule perm (banks gone).
//   Waves fully independent (finally tests R18's decoupling, with LESS state).
//   VGPR ~48 (R11 ran this inner loop + staging at 32 under (256,8)); keep (256,8).
//   Predict: LDS_Block_Size 0, VGPR 40-64, WRITE ~4MB (gate); Occupancy 75-95,
//   VALUBusy 60-75, MfmaUtil 33-38, sim -> 33-40us. If sim >= 55 (L1 thrash):
//   revert R16, declare ~110.7 ceiling.

#define N_ROWS 16384
#define DIM 128
#define JSPLIT 16
#define COLS_PER_BLOCK (N_ROWS / JSPLIT)   // 1024
#define JCHUNK 32
#define NCHUNK (COLS_PER_BLOCK / JCHUNK)   // 32
#define ROWS_PER_BLOCK 128
#define ITILES (N_ROWS / ROWS_PER_BLOCK)   // 128
#define GRID_TOTAL (ITILES * JSPLIT)       // 2048

// exp(2*sim) = 2^(SCALE*sim); SCALE baked into z1q so MFMA acc is already log2-domain.
#define SCALE 2.8853900817779268f  // 2 * log2(e)

typedef __attribute__((ext_vector_type(8))) int   int8v;   // v8i32: 32 fp8 bytes (MFMA A/B frag)
typedef __attribute__((ext_vector_type(4))) int   int4v;   // 16B granule
typedef __attribute__((ext_vector_type(4))) float floatx4; // MFMA C/D frag

#if __has_builtin(__builtin_amdgcn_exp2f)
#define EXP2(x) __builtin_amdgcn_exp2f(x)
#else
#define EXP2(x) exp2f(x)
#endif

// fmt 0 = OCP e4m3 for both A and B; scales = e8m0 1.0 in all bytes (identity).
__device__ inline floatx4 mfma_fp8_k128(int8v a, int8v b, floatx4 c) {
  return __builtin_amdgcn_mfma_scale_f32_16x16x128_f8f6f4(
      a, b, c, 0, 0, 0, 0x7F7F7F7F, 0, 0x7F7F7F7F);
}

__device__ inline short pack_fp8x2(float x, float y) {
#if __has_builtin(__builtin_amdgcn_cvt_pk_fp8_f32)
  int p = __builtin_amdgcn_cvt_pk_fp8_f32(x, y, 0, false);  // bytes 0,1 of result
  return (short)(p & 0xFFFF);
#else
  __hip_fp8_e4m3 a(x), b(y);
  return (short)((unsigned char)a.__x | ((unsigned short)(unsigned char)b.__x << 8));
#endif
}

// ---------------- Kernel 1: row norms + diagonal + fp8 cast + zero init -----
__global__ __launch_bounds__(256) void norm_kernel(
    const float* __restrict__ z1, const float* __restrict__ z2,
    unsigned char* __restrict__ z1q, unsigned char* __restrict__ z2q,
    float* __restrict__ diag, float* __restrict__ denom,
    float* __restrict__ out) {
  int tid = threadIdx.x;
  int wave = tid >> 6, lane = tid & 63;
  int row = blockIdx.x * 4 + wave;   // one wave per row
  const float2* p1 = (const float2*)(z1 + (size_t)row * DIM);
  const float2* p2 = (const float2*)(z2 + (size_t)row * DIM);
  float2 a = p1[lane], b = p2[lane];
  float s11 = a.x * a.x + a.y * a.y;
  float s22 = b.x * b.x + b.y * b.y;
  float s12 = a.x * b.x + a.y * b.y;
#pragma unroll
  for (int m = 32; m >= 1; m >>= 1) {
    s11 += __shfl_xor(s11, m);
    s22 += __shfl_xor(s22, m);
    s12 += __shfl_xor(s12, m);
  }
  float inv1 = 1.0f / fmaxf(sqrtf(s11), 1e-12f);  // torch F.normalize eps
  float inv2 = 1.0f / fmaxf(sqrtf(s22), 1e-12f);
  float sc1 = inv1 * SCALE;                        // bake exp scale into A side
  // fp8 e4m3 (OCP on gfx950): |z1q| <= SCALE ~ 2.89 << 448 max. k order: 2*lane, 2*lane+1.
  ((short*)(z1q + (size_t)row * DIM))[lane] = pack_fp8x2(a.x * sc1, a.y * sc1);
  ((short*)(z2q + (size_t)row * DIM))[lane] = pack_fp8x2(b.x * inv2, b.y * inv2);
  if (lane == 0) {
    diag[row]  = s12 * inv1 * inv2;  // exact fp32 diagonal
    denom[row] = 0.0f;
  }
  if (blockIdx.x == 0 && tid == 0) out[0] = 0.0f;
}

// ---------------- Kernel 2: denom_i += sum_j exp(2*sim_ij), MX-fp8 MFMA -----
// NO LDS, NO barriers. B-fragments read straight from global: the 4KB chunk is
// L1-resident after the first wave touches it; z2q (2MB) is L2-resident for
// cross-block reuse. Lane (q,l15) reads rows (c*32 + jj*16 + l15), 32B at q*32.
__global__ __launch_bounds__(256, 8) void sim_kernel(
    const unsigned char* __restrict__ z1q,
    const unsigned char* __restrict__ z2q,
    float* __restrict__ denom) {
  int tid = threadIdx.x;
  int w   = tid >> 6;
  int q   = (tid >> 4) & 3;   // quad within wave
  int l15 = tid & 15;
  int itile  = blockIdx.x & (ITILES - 1);
  int jsplit = blockIdx.x >> 7;          // 0..15
  int i0 = itile * ROWS_PER_BLOCK + w * 32;

  const floatx4 ZERO4 = {0.f, 0.f, 0.f, 0.f};

  // A fragments: lane (q,l15) holds bytes [q*32, q*32+32) of row (i0+ii*16+l15).
  int8v afrag[2];
#pragma unroll
  for (int ii = 0; ii < 2; ++ii) {
    const int4v* rp = (const int4v*)(z1q + (size_t)(i0 + ii * 16 + l15) * DIM);
    int4v a0 = rp[q * 2], a1 = rp[q * 2 + 1];
    int8v af;
    af[0] = a0[0]; af[1] = a0[1]; af[2] = a0[2]; af[3] = a0[3];
    af[4] = a1[0]; af[5] = a1[1]; af[6] = a1[2]; af[7] = a1[3];
    afrag[ii] = af;
  }

  floatx4 rowsum[2];
  rowsum[0] = ZERO4;
  rowsum[1] = ZERO4;
  // 2-deep carried accumulators (R16): slot ii flushes its own previous MFMA,
  // 2 tile-steps old. Static indexing only.
  floatx4 pacc0 = {-1e30f, -1e30f, -1e30f, -1e30f};
  floatx4 pacc1 = {-1e30f, -1e30f, -1e30f, -1e30f};

  // Per-lane B base: row l15 of the block's column window, byte offset q*32.
  const char* Bbase = (const char*)z2q +
      (size_t)(jsplit * COLS_PER_BLOCK + l15) * DIM + q * 32;

  // unroll 1: keep the 32-trip loop rolled (R15/R19 lesson: unrolling hoists all
  // per-chunk addresses and spills).
#pragma unroll 1
  for (int c = 0; c < NCHUNK; ++c) {
#pragma unroll
    for (int jj = 0; jj < 2; ++jj) {
      const int4v* rp =
          (const int4v*)(Bbase + (size_t)(c * JCHUNK + jj * 16) * DIM);
      int4v lo = rp[0];
      int4v hi = rp[1];
      int8v bf;
      bf[0] = lo[0]; bf[1] = lo[1]; bf[2] = lo[2]; bf[3] = lo[3];
      bf[4] = hi[0]; bf[5] = hi[1]; bf[6] = hi[2]; bf[7] = hi[3];

      // ii = 0: flush slot 0's previous tile (2 tile-steps old)
      {
        floatx4 nacc = mfma_fp8_k128(afrag[0], bf, ZERO4);
        floatx4 e;
#pragma unroll
        for (int r = 0; r < 4; ++r) e[r] = EXP2(pacc0[r]);
        rowsum[0] += e;
        pacc0 = nacc;
      }
      // ii = 1: flush slot 1's previous tile (2 tile-steps old)
      {
        floatx4 nacc = mfma_fp8_k128(afrag[1], bf, ZERO4);
        floatx4 e;
#pragma unroll
        for (int r = 0; r < 4; ++r) e[r] = EXP2(pacc1[r]);
        rowsum[1] += e;
        pacc1 = nacc;
      }
    }
  }
  // final flush of both slots
  {
    floatx4 e;
#pragma unroll
    for (int r = 0; r < 4; ++r) e[r] = EXP2(pacc0[r]);
    rowsum[0] += e;
#pragma unroll
    for (int r = 0; r < 4; ++r) e[r] = EXP2(pacc1[r]);
    rowsum[1] += e;
  }

  // reduce the 16 column-partials (spread over l15) and commit.
  // C/D layout (shape-determined): col = lane&15 (j), row = q*4 + r (i).
#pragma unroll
  for (int ii = 0; ii < 2; ++ii)
#pragma unroll
    for (int r = 0; r < 4; ++r) {
      float v = rowsum[ii][r];
      v += __shfl_xor(v, 1);
      v += __shfl_xor(v, 2);
      v += __shfl_xor(v, 4);
      v += __shfl_xor(v, 8);
      if (l15 == 0) atomicAdd(&denom[i0 + ii * 16 + q * 4 + r], v);
    }
}

// ---------------- Kernel 3: loss = -mean(2*diag - log(denom+eps)) -----------
// 64 blocks x 256 threads; one row/thread; wave-reduce then one atomicAdd/wave.
__global__ __launch_bounds__(256) void loss_kernel(
    const float* __restrict__ denom, const float* __restrict__ diag,
    float* __restrict__ out) {
  int row = blockIdx.x * 256 + threadIdx.x;
  float t = 2.0f * diag[row] - __logf(denom[row] + 1e-8f);
#pragma unroll
  for (int m = 32; m >= 1; m >>= 1) t += __shfl_xor(t, m);
  if ((threadIdx.x & 63) == 0) atomicAdd(out, -t * (1.0f / N_ROWS));
}

extern "C" void kernel_launch(void* const* d_in, const int* in_sizes, int n_in,
                              void* d_out, int out_size, void* d_ws, size_t ws_size,
                              hipStream_t stream) {
  const float* z1 = (const float*)d_in[0];
  const float* z2 = (const float*)d_in[1];
  char* ws = (char*)d_ws;
  unsigned char* z1q = (unsigned char*)ws;                                  // 2 MB
  unsigned char* z2q = (unsigned char*)(ws + (size_t)N_ROWS * DIM);         // 2 MB
  float* denom = (float*)(ws + (size_t)2 * N_ROWS * DIM);                   // 64 KB
  float* diag  = (float*)(ws + (size_t)2 * N_ROWS * DIM + (size_t)N_ROWS * 4);
  float* outp  = (float*)d_out;

  norm_kernel<<<N_ROWS / 4, 256, 0, stream>>>(z1, z2, z1q, z2q, diag, denom, outp);
  sim_kernel<<<GRID_TOTAL, 256, 0, stream>>>(z1q, z2q, denom);
  loss_kernel<<<N_ROWS / 256, 256, 0, stream>>>(denom, diag, outp);
}

// Round 12
// 109.695 us; speedup vs baseline: 1.7172x; 1.7172x over previous
//
#include <hip/hip_runtime.h>
#include <hip/hip_bf16.h>
#include <hip/hip_fp8.h>

// CrossViewContrast: loss = -mean_i( 2*<z1n_i,z2n_i> - log(sum_j exp(2*<z1n_i,z2n_j>) + 1e-8) )
// N=16384, D=128.
// R8:  MX-fp8 K=128 MFMA, 3 kernels, (256,8): sim 47.7us, total 111.5.
// R11: + stride-4 granule placement -> SQ_LDS_BANK_CONFLICT == 0. sim 47.5, total 112.2.
// R12: JCHUNK 64: NULL. R16: 2-deep pacc @(256,4), clean: NULL (47.0, total 110.7 best).
// R17: counted-vmcnt pipeline, clean: NULL (50.2). R20: oversubscribed grid, clean:
//   Occupancy 63, sim UNCHANGED. R13/R14/R15/R18/R19: VGPR spills (mechanisms untested).
// R21: NO-LDS direct-global B reads, clean (LDS 0, VGPR 32, Occ 68): REGRESSED 2.7x
//   (126us, MfmaUtil 10, VALUBusy 17). Per-wave loads with ~2 outstanding cannot
//   hide L1/L2 latency; the global_load_lds DMA + short ds_read latency is what
//   bought 47us. LDS staging stays. Theory dead.
// R22: halve DS traffic instead of removing it. Rows-per-wave 32->64 (four 16-row
//   ii slots): every wave still reads the full 4KB B-chunk, but half as many
//   (block x chunk) B-readings cover the same output. ds_read_b128 1.05M->524K
//   (per-CU DS-read ~20.5->~10us), DMA 256->128MB, grid 2048->1024 (convoy events
//   halved). VALU/trans/MFMA totals unchanged. Register-safe: R16 skeleton, all
//   state NAMED scalars (afrag0-3/pacc0-3/rowsum0-3), unroll 1 on chunk loop,
//   (256,4) cap 128 vs ~92 est.
//   GATE: VGPR 80-104, WRITE ~4MB, LDS 8192, conflicts 0. If DS co-binding:
//   sim -> 39-44us, VALUBusy 58-65, MfmaUtil 32-36. If clean-but-NULL: revert R16,
//   declare ceiling.

#define N_ROWS 16384
#define DIM 128
#define JSPLIT 16
#define COLS_PER_BLOCK (N_ROWS / JSPLIT)   // 1024
#define JCHUNK 32
#define NCHUNK (COLS_PER_BLOCK / JCHUNK)   // 32
#define ROWS_PER_BLOCK 256
#define ITILES (N_ROWS / ROWS_PER_BLOCK)   // 64
#define GRID_TOTAL (ITILES * JSPLIT)       // 1024

// exp(2*sim) = 2^(SCALE*sim); SCALE baked into z1q so MFMA acc is already log2-domain.
#define SCALE 2.8853900817779268f  // 2 * log2(e)

typedef __attribute__((ext_vector_type(8))) int   int8v;   // v8i32: 32 fp8 bytes (MFMA A/B frag)
typedef __attribute__((ext_vector_type(4))) int   int4v;   // one 16B LDS granule
typedef __attribute__((ext_vector_type(4))) float floatx4; // MFMA C/D frag

#if __has_builtin(__builtin_amdgcn_exp2f)
#define EXP2(x) __builtin_amdgcn_exp2f(x)
#else
#define EXP2(x) exp2f(x)
#endif

// fmt 0 = OCP e4m3 for both A and B; scales = e8m0 1.0 in all bytes (identity).
__device__ inline floatx4 mfma_fp8_k128(int8v a, int8v b, floatx4 c) {
  return __builtin_amdgcn_mfma_scale_f32_16x16x128_f8f6f4(
      a, b, c, 0, 0, 0, 0x7F7F7F7F, 0, 0x7F7F7F7F);
}

__device__ inline void gload_lds16(const void* gptr, void* lptr) {
  __builtin_amdgcn_global_load_lds(
      (const __attribute__((address_space(1))) void*)gptr,
      (__attribute__((address_space(3))) void*)lptr, 16, 0, 0);
}

__device__ inline short pack_fp8x2(float x, float y) {
#if __has_builtin(__builtin_amdgcn_cvt_pk_fp8_f32)
  int p = __builtin_amdgcn_cvt_pk_fp8_f32(x, y, 0, false);  // bytes 0,1 of result
  return (short)(p & 0xFFFF);
#else
  __hip_fp8_e4m3 a(x), b(y);
  return (short)((unsigned char)a.__x | ((unsigned short)(unsigned char)b.__x << 8));
#endif
}

// ---------------- Kernel 1: row norms + diagonal + fp8 cast + zero init -----
__global__ __launch_bounds__(256) void norm_kernel(
    const float* __restrict__ z1, const float* __restrict__ z2,
    unsigned char* __restrict__ z1q, unsigned char* __restrict__ z2q,
    float* __restrict__ diag, float* __restrict__ denom,
    float* __restrict__ out) {
  int tid = threadIdx.x;
  int wave = tid >> 6, lane = tid & 63;
  int row = blockIdx.x * 4 + wave;   // one wave per row
  const float2* p1 = (const float2*)(z1 + (size_t)row * DIM);
  const float2* p2 = (const float2*)(z2 + (size_t)row * DIM);
  float2 a = p1[lane], b = p2[lane];
  float s11 = a.x * a.x + a.y * a.y;
  float s22 = b.x * b.x + b.y * b.y;
  float s12 = a.x * b.x + a.y * b.y;
#pragma unroll
  for (int m = 32; m >= 1; m >>= 1) {
    s11 += __shfl_xor(s11, m);
    s22 += __shfl_xor(s22, m);
    s12 += __shfl_xor(s12, m);
  }
  float inv1 = 1.0f / fmaxf(sqrtf(s11), 1e-12f);  // torch F.normalize eps
  float inv2 = 1.0f / fmaxf(sqrtf(s22), 1e-12f);
  float sc1 = inv1 * SCALE;                        // bake exp scale into A side
  // fp8 e4m3 (OCP on gfx950): |z1q| <= SCALE ~ 2.89 << 448 max. k order: 2*lane, 2*lane+1.
  ((short*)(z1q + (size_t)row * DIM))[lane] = pack_fp8x2(a.x * sc1, a.y * sc1);
  ((short*)(z2q + (size_t)row * DIM))[lane] = pack_fp8x2(b.x * inv2, b.y * inv2);
  if (lane == 0) {
    diag[row]  = s12 * inv1 * inv2;  // exact fp32 diagonal
    denom[row] = 0.0f;
  }
  if (blockIdx.x == 0 && tid == 0) out[0] = 0.0f;
}

// ---------------- Kernel 2: denom_i += sum_j exp(2*sim_ij), MX-fp8 MFMA -----
// Granule placement: logical granule o of row r stored at physical perm(o)^(r&7),
// perm(o)=(o>>1)|((o&1)<<2). Read (lane q,l15): lo at (q^s), hi at (q^s)^4 ->
// successive ds_read_b128s hit bank-groups 4 apart; R10/R11 measured
// SQ_LDS_BANK_CONFLICT == 0 with this layout.
// Each wave owns 64 rows (ii=0..3); one bf read feeds 4 MFMAs.
__global__ __launch_bounds__(256, 4) void sim_kernel(
    const unsigned char* __restrict__ z1q,
    const unsigned char* __restrict__ z2q,
    float* __restrict__ denom) {
  __shared__ int4v lds[2][JCHUNK * 8];  // 2 x 4 KB

  int tid = threadIdx.x;
  int w   = tid >> 6;
  int q   = (tid >> 4) & 3;   // quad within wave
  int l15 = tid & 15;
  int s   = l15 & 7;          // swizzle key
  int itile  = blockIdx.x & (ITILES - 1);
  int jsplit = blockIdx.x >> 6;          // 0..15 (ITILES = 64)
  int i0 = itile * ROWS_PER_BLOCK + w * 64;   // wave owns rows i0..i0+63

  const floatx4 ZERO4 = {0.f, 0.f, 0.f, 0.f};

  // A fragments: lane (q,l15) holds bytes [q*32, q*32+32) of row (i0+ii*16+l15).
  int8v afrag0, afrag1, afrag2, afrag3;
#define LOAD_AFRAG(dst, ii)                                                  \
  do {                                                                       \
    const int4v* rp =                                                        \
        (const int4v*)(z1q + (size_t)(i0 + (ii) * 16 + l15) * DIM);          \
    int4v a0 = rp[q * 2], a1 = rp[q * 2 + 1];                                \
    int8v af;                                                                \
    af[0] = a0[0]; af[1] = a0[1]; af[2] = a0[2]; af[3] = a0[3];              \
    af[4] = a1[0]; af[5] = a1[1]; af[6] = a1[2]; af[7] = a1[3];              \
    dst = af;                                                                \
  } while (0)
  LOAD_AFRAG(afrag0, 0);
  LOAD_AFRAG(afrag1, 1);
  LOAD_AFRAG(afrag2, 2);
  LOAD_AFRAG(afrag3, 3);

  floatx4 rowsum0 = ZERO4, rowsum1 = ZERO4, rowsum2 = ZERO4, rowsum3 = ZERO4;
  // Per-slot carried accumulators: slot ii flushes its own previous MFMA, now
  // 8 MFMA-steps old when consumed -> latency fully drained. All named scalars.
  floatx4 pacc0 = {-1e30f, -1e30f, -1e30f, -1e30f};
  floatx4 pacc1 = {-1e30f, -1e30f, -1e30f, -1e30f};
  floatx4 pacc2 = {-1e30f, -1e30f, -1e30f, -1e30f};
  floatx4 pacc3 = {-1e30f, -1e30f, -1e30f, -1e30f};

  const char* Bbase = (const char*)z2q + (size_t)jsplit * COLS_PER_BLOCK * DIM;

  // stage one 4 KB chunk: 256 thr x 16 B, lane-linear LDS dest (constraint).
  // physical slot gl of row holds logical o = inv_perm(gl ^ (row&7)):
  //   u = gl ^ (row&7); o = 2*(u&3) + (u>>2)
#define STAGE(cidx, bufi)                                                    \
  do {                                                                       \
    const char* _ck = Bbase + (size_t)(cidx) * JCHUNK * DIM;                 \
    char* _dst = (char*)&lds[bufi][0];                                       \
    int _row = tid >> 3, _gl = tid & 7;                                      \
    int _u = _gl ^ (_row & 7);                                               \
    int _o = 2 * (_u & 3) + (_u >> 2);                                       \
    gload_lds16(_ck + (size_t)_row * DIM + _o * 16,                          \
                _dst + (size_t)tid * 16);                                    \
  } while (0)

  STAGE(0, 0);
  __syncthreads();

  int lo_i = q ^ s;       // physical granule of logical 2q
  int hi_i = lo_i ^ 4;    // physical granule of logical 2q+1 (stride-4 apart)

#define MFMA_FLUSH(af, pacc, rowsum)                                         \
  do {                                                                       \
    floatx4 nacc = mfma_fp8_k128(af, bf, ZERO4);                             \
    floatx4 e;                                                               \
    _Pragma("unroll")                                                        \
    for (int r = 0; r < 4; ++r) e[r] = EXP2(pacc[r]);                        \
    rowsum += e;                                                             \
    pacc = nacc;                                                             \
  } while (0)

  // keep the 32-trip loop rolled (R15/R19 lesson: unrolling hoists addresses
  // past the VGPR cap and spills).
#pragma unroll 1
  for (int c = 0; c < NCHUNK; ++c) {
    if (c + 1 < NCHUNK) STAGE(c + 1, (c + 1) & 1);
    const int4v* buf = &lds[c & 1][0];

#pragma unroll
    for (int jj = 0; jj < 2; ++jj) {
      int rbase = (jj * 16 + l15) * 8;
      int4v lo = buf[rbase + lo_i];
      int4v hi = buf[rbase + hi_i];
      int8v bf;
      bf[0] = lo[0]; bf[1] = lo[1]; bf[2] = lo[2]; bf[3] = lo[3];
      bf[4] = hi[0]; bf[5] = hi[1]; bf[6] = hi[2]; bf[7] = hi[3];

      MFMA_FLUSH(afrag0, pacc0, rowsum0);
      MFMA_FLUSH(afrag1, pacc1, rowsum1);
      MFMA_FLUSH(afrag2, pacc2, rowsum2);
      MFMA_FLUSH(afrag3, pacc3, rowsum3);
    }
    __syncthreads();  // guards buf reuse
  }
  // final flush of all four slots
  {
    floatx4 e;
#pragma unroll
    for (int r = 0; r < 4; ++r) e[r] = EXP2(pacc0[r]);
    rowsum0 += e;
#pragma unroll
    for (int r = 0; r < 4; ++r) e[r] = EXP2(pacc1[r]);
    rowsum1 += e;
#pragma unroll
    for (int r = 0; r < 4; ++r) e[r] = EXP2(pacc2[r]);
    rowsum2 += e;
#pragma unroll
    for (int r = 0; r < 4; ++r) e[r] = EXP2(pacc3[r]);
    rowsum3 += e;
  }

  // reduce the 16 column-partials (spread over l15) and commit.
  // C/D layout (shape-determined): col = lane&15 (j), row = q*4 + r (i).
#define COMMIT(rowsum, ii)                                                   \
  do {                                                                       \
    _Pragma("unroll")                                                        \
    for (int r = 0; r < 4; ++r) {                                            \
      float v = rowsum[r];                                                   \
      v += __shfl_xor(v, 1);                                                 \
      v += __shfl_xor(v, 2);                                                 \
      v += __shfl_xor(v, 4);                                                 \
      v += __shfl_xor(v, 8);                                                 \
      if (l15 == 0) atomicAdd(&denom[i0 + (ii) * 16 + q * 4 + r], v);        \
    }                                                                        \
  } while (0)
  COMMIT(rowsum0, 0);
  COMMIT(rowsum1, 1);
  COMMIT(rowsum2, 2);
  COMMIT(rowsum3, 3);
}

// ---------------- Kernel 3: loss = -mean(2*diag - log(denom+eps)) -----------
// 64 blocks x 256 threads; one row/thread; wave-reduce then one atomicAdd/wave.
__global__ __launch_bounds__(256) void loss_kernel(
    const float* __restrict__ denom, const float* __restrict__ diag,
    float* __restrict__ out) {
  int row = blockIdx.x * 256 + threadIdx.x;
  float t = 2.0f * diag[row] - __logf(denom[row] + 1e-8f);
#pragma unroll
  for (int m = 32; m >= 1; m >>= 1) t += __shfl_xor(t, m);
  if ((threadIdx.x & 63) == 0) atomicAdd(out, -t * (1.0f / N_ROWS));
}

extern "C" void kernel_launch(void* const* d_in, const int* in_sizes, int n_in,
                              void* d_out, int out_size, void* d_ws, size_t ws_size,
                              hipStream_t stream) {
  const float* z1 = (const float*)d_in[0];
  const float* z2 = (const float*)d_in[1];
  char* ws = (char*)d_ws;
  unsigned char* z1q = (unsigned char*)ws;                                  // 2 MB
  unsigned char* z2q = (unsigned char*)(ws + (size_t)N_ROWS * DIM);         // 2 MB
  float* denom = (float*)(ws + (size_t)2 * N_ROWS * DIM);                   // 64 KB
  float* diag  = (float*)(ws + (size_t)2 * N_ROWS * DIM + (size_t)N_ROWS * 4);
  float* outp  = (float*)d_out;

  norm_kernel<<<N_ROWS / 4, 256, 0, stream>>>(z1, z2, z1q, z2q, diag, denom, outp);
  sim_kernel<<<GRID_TOTAL, 256, 0, stream>>>(z1q, z2q, denom);
  loss_kernel<<<N_ROWS / 256, 256, 0, stream>>>(denom, diag, outp);
}